// Round 7
// baseline (22.672 us; speedup 1.0000x reference)
//
#include <hip/hip_runtime.h>

// SATD loss: per 8x8 block of (input-label), t = H*blk*H (H = Sylvester
// Hadamard), result = mean(|t|).
// R7: wave-count experiment. Each 8row x 256col stripe is split between a
// WAVE PAIR (4 rows each) -> 12288 waves (8/SIMD, 32 waves/CU resident cap)
// vs 6144 before. Row FHT: shfl_xor(1) stage + 2 in-register stages. The
// halves exchange post-row-FHT values via LDS (b128, conflict-free), then
// each wave does the full 8-point column FHT per col and abs-sums its own
// 4 output rows. Partials -> d_ws; 1-wave final kernel reduces.

#define N_TOTAL ((float)(16LL * 3 * 512 * 512))   // 12,582,912
#define GRID1 3072

__global__ __launch_bounds__(256, 8) void satd_partial(const float* __restrict__ a,
                                                       const float* __restrict__ b,
                                                       float* __restrict__ ws) {
    const int lane = threadIdx.x & 63;
    const int wid  = threadIdx.x >> 6;
    const int pl   = wid >> 1;                  // pair-local index (0,1)
    const int h    = wid & 1;                   // half: 0 -> rows 0-3, 1 -> rows 4-7
    const int s    = blockIdx.x * 2 + pl;       // stripe id, [0, 6144)
    const int xh   = s & 1;                     // which 256-col half
    const int y8   = (s >> 1) & 63;             // block-row
    const int img  = s >> 7;                    // b*c image, [0, 48)

    const size_t base = (size_t)img * (512 * 512)
                      + (size_t)(y8 * 8 + h * 4) * 512 + (size_t)(xh * 256)
                      + (lane << 2);

    float4 av[4], bv[4];
#pragma unroll
    for (int i = 0; i < 4; ++i) {
        av[i] = *reinterpret_cast<const float4*>(a + base + (size_t)(i * 512));
        bv[i] = *reinterpret_cast<const float4*>(b + base + (size_t)(i * 512));
    }

    float v[4][4];
#pragma unroll
    for (int r = 0; r < 4; ++r) {
        v[r][0] = av[r].x - bv[r].x;
        v[r][1] = av[r].y - bv[r].y;
        v[r][2] = av[r].z - bv[r].z;
        v[r][3] = av[r].w - bv[r].w;
    }

    // ---- row FHT stage 4: global cols c <-> c+4 live in lanes L / L^1 ----
    const float sx = (lane & 1) ? -1.0f : 1.0f;   // hi lane: p - x
#pragma unroll
    for (int r = 0; r < 4; ++r)
#pragma unroll
        for (int c = 0; c < 4; ++c) {
            float p = __shfl_xor(v[r][c], 1);
            v[r][c] = fmaf(sx, v[r][c], p);
        }

    // ---- row FHT stages 2,1 (local cols) ----
#pragma unroll
    for (int r = 0; r < 4; ++r) {
        float u0 = v[r][0], u1 = v[r][1], u2 = v[r][2], u3 = v[r][3];
        float t0 = u0 + u2, t2 = u0 - u2, t1 = u1 + u3, t3 = u1 - u3;
        v[r][0] = t0 + t1; v[r][1] = t0 - t1;
        v[r][2] = t2 + t3; v[r][3] = t2 - t3;
    }

    // ---- exchange halves through LDS (conflict-free b128) ----
    __shared__ float4 xch[2][8][64];   // [pair][row][lane] = 16 KB
#pragma unroll
    for (int r = 0; r < 4; ++r)
        xch[pl][h * 4 + r][lane] = make_float4(v[r][0], v[r][1], v[r][2], v[r][3]);
    __syncthreads();

    float o[4][4];
#pragma unroll
    for (int r = 0; r < 4; ++r) {
        float4 q = xch[pl][(1 - h) * 4 + r][lane];
        o[r][0] = q.x; o[r][1] = q.y; o[r][2] = q.z; o[r][3] = q.w;
    }

    // ---- full 8-point column FHT per col; abs-sum own half of outputs ----
    float acc = 0.0f;
#pragma unroll
    for (int c = 0; c < 4; ++c) {
        float x0, x1, x2, x3, x4, x5, x6, x7;
        if (h == 0) { x0 = v[0][c]; x1 = v[1][c]; x2 = v[2][c]; x3 = v[3][c];
                      x4 = o[0][c]; x5 = o[1][c]; x6 = o[2][c]; x7 = o[3][c]; }
        else        { x0 = o[0][c]; x1 = o[1][c]; x2 = o[2][c]; x3 = o[3][c];
                      x4 = v[0][c]; x5 = v[1][c]; x6 = v[2][c]; x7 = v[3][c]; }
        float y0 = x0 + x4, y4 = x0 - x4, y1 = x1 + x5, y5 = x1 - x5;
        float y2 = x2 + x6, y6 = x2 - x6, y3 = x3 + x7, y7 = x3 - x7;
        if (h == 0) {
            float z0 = y0 + y2, z2 = y0 - y2, z1 = y1 + y3, z3 = y1 - y3;
            acc += fabsf(z0 + z1) + fabsf(z0 - z1) + fabsf(z2 + z3) + fabsf(z2 - z3);
        } else {
            float z4 = y4 + y6, z6 = y4 - y6, z5 = y5 + y7, z7 = y5 - y7;
            acc += fabsf(z4 + z5) + fabsf(z4 - z5) + fabsf(z6 + z7) + fabsf(z6 - z7);
        }
    }

    // ---- 64-lane wave reduction ----
#pragma unroll
    for (int off = 32; off >= 1; off >>= 1) acc += __shfl_down(acc, off);

    __shared__ float red[4];
    if (lane == 0) red[wid] = acc;
    __syncthreads();
    if (threadIdx.x == 0)
        ws[blockIdx.x] = red[0] + red[1] + red[2] + red[3];
}

__global__ __launch_bounds__(64) void satd_final(const float* __restrict__ ws,
                                                 float* __restrict__ out) {
    const int t = threadIdx.x;
    float s_ = 0.0f;
#pragma unroll
    for (int k = 0; k < GRID1 / 64; ++k) s_ += ws[t + 64 * k];

#pragma unroll
    for (int off = 32; off >= 1; off >>= 1) s_ += __shfl_down(s_, off);

    if (t == 0) out[0] = s_ * (1.0f / N_TOTAL);
}

extern "C" void kernel_launch(void* const* d_in, const int* in_sizes, int n_in,
                              void* d_out, int out_size, void* d_ws, size_t ws_size,
                              hipStream_t stream) {
    const float* a = (const float*)d_in[0];   // input
    const float* b = (const float*)d_in[1];   // label
    float* out = (float*)d_out;
    float* ws  = (float*)d_ws;                // 3072 floats of scratch

    satd_partial<<<dim3(GRID1), dim3(256), 0, stream>>>(a, b, ws);
    satd_final<<<dim3(1), dim3(64), 0, stream>>>(ws, out);
}

// Round 9
// 20.306 us; speedup vs baseline: 1.1166x; 1.1166x over previous
//
#include <hip/hip_runtime.h>

// SATD loss: per 8x8 block of (input-label), t = H*blk*H (H = Sylvester
// Hadamard), result = mean(|t|).
// R9: R6 structure (best: 22.5us), single change: all 16 input loads are
// NON-TEMPORAL (global_load_dwordx4 ... nt -> no L1 allocation). Theory:
// stream is LLC-resident on replays yet only ~5.2 TB/s; ~19.6 B/cyc/CU ~
// 1 line/3.3cyc suggests the L1 line-fill path serializes a zero-reuse
// stream. (R8 failed compile: builtin needs a native vector type, not
// HIP_vector_type struct -> use ext_vector_type(4) float.)

#define N_TOTAL ((float)(16LL * 3 * 512 * 512))   // 12,582,912
#define GRID1 1536

typedef float vfloat4 __attribute__((ext_vector_type(4)));

__global__ __launch_bounds__(256) void satd_partial(const float* __restrict__ a,
                                                    const float* __restrict__ b,
                                                    float* __restrict__ ws) {
    const int lane = threadIdx.x & 63;
    const int wid  = threadIdx.x >> 6;
    const int s    = blockIdx.x * 4 + wid;      // stripe id, [0, 6144)
    const int xh   = s & 1;                     // which 256-col half
    const int y8   = (s >> 1) & 63;             // block-row
    const int img  = s >> 7;                    // b*c image, [0, 48)

    const size_t base = (size_t)img * (512 * 512)
                      + (size_t)(y8 * 8) * 512 + (size_t)(xh * 256) + (lane << 2);

    vfloat4 av[8], bv[8];
#pragma unroll
    for (int i = 0; i < 8; ++i) {
        av[i] = __builtin_nontemporal_load(
                    reinterpret_cast<const vfloat4*>(a + base + (size_t)(i * 512)));
        bv[i] = __builtin_nontemporal_load(
                    reinterpret_cast<const vfloat4*>(b + base + (size_t)(i * 512)));
    }

    float v[8][4];
#pragma unroll
    for (int r = 0; r < 8; ++r) {
        v[r][0] = av[r].x - bv[r].x;
        v[r][1] = av[r].y - bv[r].y;
        v[r][2] = av[r].z - bv[r].z;
        v[r][3] = av[r].w - bv[r].w;
    }

    // ---- row FHT stage 4: global cols c <-> c+4 live in lanes L / L^1 ----
    const float sx = (lane & 1) ? -1.0f : 1.0f;   // hi lane: p - x
#pragma unroll
    for (int r = 0; r < 8; ++r)
#pragma unroll
        for (int c = 0; c < 4; ++c) {
            float p = __shfl_xor(v[r][c], 1);
            v[r][c] = fmaf(sx, v[r][c], p);
        }

    // ---- row FHT stages 2,1 (local cols) ----
#pragma unroll
    for (int r = 0; r < 8; ++r) {
        float u0 = v[r][0], u1 = v[r][1], u2 = v[r][2], u3 = v[r][3];
        float t0 = u0 + u2, t2 = u0 - u2, t1 = u1 + u3, t3 = u1 - u3;
        v[r][0] = t0 + t1; v[r][1] = t0 - t1;
        v[r][2] = t2 + t3; v[r][3] = t2 - t3;
    }

    // ---- column FHT (8 rows in-register) + abs-accumulate ----
    float acc = 0.0f;
#pragma unroll
    for (int c = 0; c < 4; ++c) {
        float x0 = v[0][c], x1 = v[1][c], x2 = v[2][c], x3 = v[3][c];
        float x4 = v[4][c], x5 = v[5][c], x6 = v[6][c], x7 = v[7][c];
        float y0 = x0 + x4, y4 = x0 - x4, y1 = x1 + x5, y5 = x1 - x5;
        float y2 = x2 + x6, y6 = x2 - x6, y3 = x3 + x7, y7 = x3 - x7;
        float z0 = y0 + y2, z2 = y0 - y2, z1 = y1 + y3, z3 = y1 - y3;
        float z4 = y4 + y6, z6 = y4 - y6, z5 = y5 + y7, z7 = y5 - y7;
        acc += fabsf(z0 + z1) + fabsf(z0 - z1) + fabsf(z2 + z3) + fabsf(z2 - z3)
             + fabsf(z4 + z5) + fabsf(z4 - z5) + fabsf(z6 + z7) + fabsf(z6 - z7);
    }

    // ---- 64-lane wave reduction ----
#pragma unroll
    for (int off = 32; off >= 1; off >>= 1) acc += __shfl_down(acc, off);

    __shared__ float red[4];
    if (lane == 0) red[wid] = acc;
    __syncthreads();
    if (threadIdx.x == 0)
        ws[blockIdx.x] = red[0] + red[1] + red[2] + red[3];
}

__global__ __launch_bounds__(64) void satd_final(const float* __restrict__ ws,
                                                 float* __restrict__ out) {
    const int t = threadIdx.x;
    float s_ = 0.0f;
#pragma unroll
    for (int k = 0; k < GRID1 / 64; ++k) s_ += ws[t + 64 * k];

#pragma unroll
    for (int off = 32; off >= 1; off >>= 1) s_ += __shfl_down(s_, off);

    if (t == 0) out[0] = s_ * (1.0f / N_TOTAL);
}

extern "C" void kernel_launch(void* const* d_in, const int* in_sizes, int n_in,
                              void* d_out, int out_size, void* d_ws, size_t ws_size,
                              hipStream_t stream) {
    const float* a = (const float*)d_in[0];   // input
    const float* b = (const float*)d_in[1];   // label
    float* out = (float*)d_out;
    float* ws  = (float*)d_ws;                // 1536 floats of scratch

    satd_partial<<<dim3(GRID1), dim3(256), 0, stream>>>(a, b, ws);
    satd_final<<<dim3(1), dim3(64), 0, stream>>>(ws, out);
}